// Round 3
// baseline (84.446 us; speedup 1.0000x reference)
//
#include <hip/hip_runtime.h>
#include <hip/hip_bf16.h>

#define WB 8192
#define WD 128
#define WC 100
#define NSPLIT 32
#define JSPL (WB/NSPLIT)   // 256 j per split
#define NTT (JSPL/16)      // 16 j-steps of 16 rows

typedef __attribute__((ext_vector_type(8))) short short8v;
typedef __attribute__((ext_vector_type(4))) float float4v;

#define SQS 3.798282f                 // sqrt((1/TAU)/ln2): fold scale into bf16 z
#define LN2F 0.69314718055994531f

// ---- workspace layout (bytes) ----
#define WS_ZBF   0u          // bf16 z (pre-scaled): 8192*128*2 = 2097152
#define WS_S     2097152u    // S[100][128] f32 = 51200
#define WS_CNT   2148352u    // cnt[128] int
#define WS_ACC   2148864u    // accf, accn
#define WS_PART  2149120u    // partials[NSPLIT][8192] float2 = 2097152

__device__ __forceinline__ unsigned short f2bf(float x){
  unsigned u = __float_as_uint(x);
  u += 0x7fffu + ((u>>16)&1u);      // RNE
  return (unsigned short)(u>>16);
}

// convert+prescale z -> bf16; block 0 also zeroes S/cnt/acc
__global__ __launch_bounds__(256) void k_prep(const float* __restrict__ z,
                                              unsigned short* __restrict__ zbf,
                                              float* __restrict__ S,
                                              float* accf, int* accn, int* cnt){
  int idx = blockIdx.x*256 + threadIdx.x;     // 131072 threads, 8 elems each
  const float4* zi = (const float4*)z;
  float4 a = zi[idx*2], b = zi[idx*2+1];
  uint4 o;
  o.x = (unsigned)f2bf(a.x*SQS) | ((unsigned)f2bf(a.y*SQS)<<16);
  o.y = (unsigned)f2bf(a.z*SQS) | ((unsigned)f2bf(a.w*SQS)<<16);
  o.z = (unsigned)f2bf(b.x*SQS) | ((unsigned)f2bf(b.y*SQS)<<16);
  o.w = (unsigned)f2bf(b.z*SQS) | ((unsigned)f2bf(b.w*SQS)<<16);
  ((uint4*)zbf)[idx] = o;
  if (blockIdx.x == 0){
    for (int i = threadIdx.x; i < WC*WD; i += 256) S[i] = 0.f;
    if (threadIdx.x < 128) cnt[threadIdx.x] = 0;
    if (threadIdx.x == 0){ accf[0] = 0.f; accn[0] = 0; }
  }
}

// class sums: 256 blocks, each 32 rows x 128 cols into LDS table, flush present classes
__global__ __launch_bounds__(256) void k_csum(const float* __restrict__ z,
                                              const int* __restrict__ labels,
                                              float* __restrict__ S,
                                              int* __restrict__ cnt){
  __shared__ float sacc[WC*WD];
  __shared__ int slab[32];
  __shared__ int slcnt[WC];
  const int t = threadIdx.x;
  const int rowBase = blockIdx.x*32;
  for (int i = t; i < WC*WD; i += 256) sacc[i] = 0.f;
  if (t < WC) slcnt[t] = 0;
  if (t < 32) slab[t] = labels[rowBase + t];
  __syncthreads();
  const int col = t & 127, rsub = t >> 7;
  #pragma unroll 4
  for (int r = 0; r < 32; r += 2){
    int row = r + rsub;
    atomicAdd(&sacc[slab[row]*WD + col], z[(size_t)(rowBase+row)*WD + col]);
  }
  if (t < 32) atomicAdd(&slcnt[slab[t]], 1);
  __syncthreads();
  for (int i = t; i < WC*WD; i += 256){
    int c = i >> 7;
    if (slcnt[c] > 0) atomicAdd(&S[i], sacc[i]);
  }
  if (t < WC && slcnt[t] > 0) atomicAdd(&cnt[t], slcnt[t]);
}

// main LSE kernel: grid (32 anchor-blocks, NSPLIT) x 256 threads (4 indep waves)
// wave owns 64 anchors; streams j in 16-row steps, frags direct from L2.
__global__ __launch_bounds__(256) void k_lse(const unsigned short* __restrict__ zbf,
                                             float2* __restrict__ part){
  const int t = threadIdx.x;
  const int wv = t>>6, lane = t&63;
  const int awave = blockIdx.x*256 + wv*64;
  const int split = blockIdx.y;
  const int j0 = split*JSPL;
  const int lg = lane>>4, ln = lane&15;

  // anchor B-fragments: B[k][n]; lane: n=ln, k=kk*32+lg*8+e
  short8v bf[4][4];
  #pragma unroll
  for (int ss = 0; ss < 4; ss++){
    const unsigned short* zr = zbf + (size_t)(awave + ss*16 + ln)*WD;
    #pragma unroll
    for (int kk = 0; kk < 4; kk++)
      bf[ss][kk] = *(const short8v*)(zr + kk*32 + lg*8);
  }

  float m[4], l[4];
  #pragma unroll
  for (int ss = 0; ss < 4; ss++){ m[ss] = -INFINITY; l[ss] = 0.f; }

  // A-frag base: row j0+ln, element chunk lg*8
  const unsigned short* ap = zbf + (size_t)(j0+ln)*WD + lg*8;

  short8v afA[4], afB[4];
#define LOADA(dst, tt) { const unsigned short* p_ = ap + (size_t)(tt)*16*WD; \
    dst[0] = *(const short8v*)(p_);      dst[1] = *(const short8v*)(p_+32);  \
    dst[2] = *(const short8v*)(p_+64);   dst[3] = *(const short8v*)(p_+96); }

#define COMPUTE(af, tt) { \
    const int jb = j0 + (tt)*16; \
    _Pragma("unroll") \
    for (int ss = 0; ss < 4; ss++){ \
      float4v acc = {0.f,0.f,0.f,0.f}; \
      _Pragma("unroll") \
      for (int kk = 0; kk < 4; kk++) \
        acc = __builtin_amdgcn_mfma_f32_16x16x32_bf16(af[kk], bf[ss][kk], acc, 0,0,0); \
      float v0 = acc[0], v1 = acc[1], v2 = acc[2], v3 = acc[3]; \
      if (jb == awave + ss*16){ \
        int r0 = lg*4; \
        if (r0+0 == ln) v0 = -INFINITY; \
        if (r0+1 == ln) v1 = -INFINITY; \
        if (r0+2 == ln) v2 = -INFINITY; \
        if (r0+3 == ln) v3 = -INFINITY; \
      } \
      float tmax = fmaxf(fmaxf(fmaxf(v0,v1),v2),v3); \
      if (__any(tmax > m[ss] + 8.0f)){ \
        float mn = fmaxf(m[ss], tmax); \
        l[ss] *= exp2f(m[ss]-mn); \
        m[ss] = mn; \
      } \
      l[ss] += (exp2f(v0-m[ss]) + exp2f(v1-m[ss])) \
             + (exp2f(v2-m[ss]) + exp2f(v3-m[ss])); \
    } }

  LOADA(afA, 0);
  for (int tt = 0; tt < NTT; tt += 2){
    LOADA(afB, tt+1);
    COMPUTE(afA, tt);
    if (tt+2 < NTT) LOADA(afA, tt+2);
    COMPUTE(afB, tt+1);
  }
#undef LOADA
#undef COMPUTE

  // combine lanes {x, x^16, x^32} (same anchor, different j-rows)
  #pragma unroll
  for (int ss = 0; ss < 4; ss++){
    float mm = m[ss], ll = l[ss];
    #pragma unroll
    for (int off = 16; off < 64; off <<= 1){
      float mo = __shfl_xor(mm, off);
      float lo = __shfl_xor(ll, off);
      float M = fmaxf(mm, mo);
      ll = ll*exp2f(mm-M) + lo*exp2f(mo-M);
      mm = M;
    }
    if (lane < 16)
      part[(size_t)split*WB + awave + ss*16 + lane] = make_float2(mm, ll);
  }
}

__global__ __launch_bounds__(256) void k_final(const float* __restrict__ z,
                                               const int* __restrict__ labels,
                                               const float* __restrict__ S,
                                               const int* __restrict__ cnt,
                                               const float2* __restrict__ part,
                                               float* __restrict__ accf,
                                               int* __restrict__ accn){
  int i = blockIdx.x*256 + threadIdx.x;
  float mm = -INFINITY, ll = 0.f;
  for (int sp = 0; sp < NSPLIT; sp++){
    float2 p = part[(size_t)sp*WB + i];
    float M = fmaxf(mm, p.x);
    ll = ll*exp2f(mm-M) + p.y*exp2f(p.x-M);
    mm = M;
  }
  float lse = (mm + log2f(ll)) * LN2F;          // natural-log LSE
  int lab = labels[i];
  const float4* zi = (const float4*)(z + (size_t)i*WD);
  const float4* sc = (const float4*)(S + (size_t)lab*WD);
  float pd = 0.f, sd = 0.f;
  #pragma unroll 8
  for (int k = 0; k < WD/4; k++){
    float4 a = zi[k], b = sc[k];
    pd += a.x*b.x + a.y*b.y + a.z*b.z + a.w*b.w;
    sd += a.x*a.x + a.y*a.y + a.z*a.z + a.w*a.w;
  }
  int np = cnt[lab] - 1;
  float loss = 0.f, val = 0.f;
  if (np > 0){ loss = lse - (pd - sd)*10.0f/(float)np; val = 1.f; }
  #pragma unroll
  for (int off = 32; off > 0; off >>= 1){
    loss += __shfl_down(loss, off);
    val  += __shfl_down(val,  off);
  }
  __shared__ float sl[4], sv[4];
  int wv = threadIdx.x>>6, lane = threadIdx.x&63;
  if (lane == 0){ sl[wv] = loss; sv[wv] = val; }
  __syncthreads();
  if (threadIdx.x == 0){
    atomicAdd(accf, sl[0]+sl[1]+sl[2]+sl[3]);
    atomicAdd(accn, (int)(sv[0]+sv[1]+sv[2]+sv[3] + 0.5f));
  }
}

__global__ void k_out(const float* accf, const int* accn, float* out){
  out[0] = accf[0] / (float)max(accn[0], 1);
}

extern "C" void kernel_launch(void* const* d_in, const int* in_sizes, int n_in,
                              void* d_out, int out_size, void* d_ws, size_t ws_size,
                              hipStream_t stream){
  const float* z = (const float*)d_in[0];
  const int* labels = (const int*)d_in[1];
  char* ws = (char*)d_ws;
  unsigned short* zbf = (unsigned short*)(ws + WS_ZBF);
  float* S     = (float*)(ws + WS_S);
  int*   cnt   = (int*)(ws + WS_CNT);
  float* accf  = (float*)(ws + WS_ACC);
  int*   accn  = (int*)(ws + WS_ACC + 4);
  float2* part = (float2*)(ws + WS_PART);
  float* out = (float*)d_out;

  hipLaunchKernelGGL(k_prep,  dim3(512),            dim3(256), 0, stream, z, zbf, S, accf, accn, cnt);
  hipLaunchKernelGGL(k_csum,  dim3(256),            dim3(256), 0, stream, z, labels, S, cnt);
  hipLaunchKernelGGL(k_lse,   dim3(WB/256, NSPLIT), dim3(256), 0, stream, zbf, part);
  hipLaunchKernelGGL(k_final, dim3(WB/256),         dim3(256), 0, stream, z, labels, S, cnt, part, accf, accn);
  hipLaunchKernelGGL(k_out,   dim3(1),              dim3(1),   0, stream, accf, accn, out);
}